// Round 2
// baseline (885.998 us; speedup 1.0000x reference)
//
#include <hip/hip_runtime.h>
#include <stdint.h>

#define BB 2
#define TT 1024
#define CC 2048
#define HH 32
#define NNH 64
#define FFD 8192
#define MTOT (BB*TT)    // 2048 rows
#define LNEPS 1e-5f
#define LOG2E 1.44269504088896340736f

typedef __attribute__((ext_vector_type(8))) __bf16 bf16x8;
typedef __attribute__((ext_vector_type(4))) float f32x4;

#define USE_GLL 1
typedef __attribute__((address_space(1))) void GAS;
typedef __attribute__((address_space(3))) void LAS;

__device__ inline void gload_lds16(const uint16_t* g, uint16_t* l) {
#if USE_GLL
  __builtin_amdgcn_global_load_lds((GAS*)g, (LAS*)l, 16, 0, 0);
#else
  *(uint4*)l = *(const uint4*)g;
#endif
}

__device__ inline float bf2f(uint32_t u) {
  union { uint32_t i; float f; } v; v.i = u << 16; return v.f;
}
__device__ inline uint16_t f2bf(float f) {
  union { float f; uint32_t i; } v; v.f = f;
  uint32_t r = v.i + 0x7FFFu + ((v.i >> 16) & 1u);
  return (uint16_t)(r >> 16);
}
__device__ inline void unpack8(uint4 d, float* v) {
  v[0] = bf2f(d.x & 0xffffu); v[1] = bf2f(d.x >> 16);
  v[2] = bf2f(d.y & 0xffffu); v[3] = bf2f(d.y >> 16);
  v[4] = bf2f(d.z & 0xffffu); v[5] = bf2f(d.z >> 16);
  v[6] = bf2f(d.w & 0xffffu); v[7] = bf2f(d.w >> 16);
}
__device__ inline uint4 pack8(const float* v) {
  uint4 d;
  d.x = (uint32_t)f2bf(v[0]) | ((uint32_t)f2bf(v[1]) << 16);
  d.y = (uint32_t)f2bf(v[2]) | ((uint32_t)f2bf(v[3]) << 16);
  d.z = (uint32_t)f2bf(v[4]) | ((uint32_t)f2bf(v[5]) << 16);
  d.w = (uint32_t)f2bf(v[6]) | ((uint32_t)f2bf(v[7]) << 16);
  return d;
}

// flag-aware loads for d_in buffers (fl=1 -> fp32, fl=0 -> bf16)
__device__ inline void load8f(const void* p, size_t idx, int fl, float* v) {
  if (fl) {
    const float* q = (const float*)p + idx;
    float4 a = *(const float4*)q; float4 b = *(const float4*)(q + 4);
    v[0]=a.x; v[1]=a.y; v[2]=a.z; v[3]=a.w; v[4]=b.x; v[5]=b.y; v[6]=b.z; v[7]=b.w;
  } else {
    unpack8(*(const uint4*)((const uint16_t*)p + idx), v);
  }
}
__device__ inline float load1f(const void* p, size_t idx, int fl) {
  return fl ? ((const float*)p)[idx] : bf2f(((const uint16_t*)p)[idx]);
}

// ---------------- dtype probe ----------------
__global__ void probe_kernel(const uint16_t* __restrict__ x, int* __restrict__ flag) {
  int tid = threadIdx.x; // 64
  float m = 0.f;
  for (int i = tid; i < 4096; i += 64) {
    float a = fabsf(bf2f(x[i]));
    if (a > m) m = a;       // NaN-safe: comparison false for NaN
  }
  for (int o = 32; o; o >>= 1) { float t = __shfl_down(m, o); if (t > m) m = t; }
  if (tid == 0) *flag = (m > 1e6f) ? 1 : 0;
}

// ---------------- LayerNorm ----------------
// INMODE 0: x from d_in (flag-aware). INMODE 1: x internal fp32.
template<int INMODE>
__global__ __launch_bounds__(256) void ln_kernel(const void* __restrict__ x,
    const void* __restrict__ g, const void* __restrict__ b,
    uint16_t* __restrict__ out, const int* __restrict__ dflag)
{
  int fl = *dflag;
  int row = blockIdx.x;
  int tid = threadIdx.x;
  int lane = tid & 63, wave = tid >> 6;
  size_t base = (size_t)row * CC + (size_t)tid * 8;
  float v[8];
  if constexpr (INMODE == 1) {
    const float* q = (const float*)x + base;
    float4 a = *(const float4*)q; float4 c = *(const float4*)(q + 4);
    v[0]=a.x; v[1]=a.y; v[2]=a.z; v[3]=a.w; v[4]=c.x; v[5]=c.y; v[6]=c.z; v[7]=c.w;
  } else {
    load8f(x, base, fl, v);
  }
  float s = 0.f, s2 = 0.f;
  #pragma unroll
  for (int j = 0; j < 8; j++) { s += v[j]; s2 += v[j] * v[j]; }
  for (int o = 32; o; o >>= 1) { s += __shfl_down(s, o); s2 += __shfl_down(s2, o); }
  __shared__ float red[8];
  if (lane == 0) { red[wave] = s; red[wave + 4] = s2; }
  __syncthreads();
  s  = red[0] + red[1] + red[2] + red[3];
  s2 = red[4] + red[5] + red[6] + red[7];
  float mean = s * (1.0f / CC);
  float var  = s2 * (1.0f / CC) - mean * mean;
  float rstd = rsqrtf(fmaxf(var, 0.f) + LNEPS);
  float gj[8], bj[8];
  load8f(g, (size_t)tid * 8, fl, gj);
  load8f(b, (size_t)tid * 8, fl, bj);
  float o8[8];
  #pragma unroll
  for (int j = 0; j < 8; j++) o8[j] = (v[j] - mean) * rstd * gj[j] + bj[j];
  *(uint4*)(out + base) = pack8(o8);
}

// ---------------- time-shift mixes ----------------
__global__ __launch_bounds__(256) void mix4_kernel(const uint16_t* __restrict__ xl,
    const void* __restrict__ tmr, const void* __restrict__ tmk,
    const void* __restrict__ tmv, const void* __restrict__ tmg,
    uint16_t* __restrict__ out, const int* __restrict__ dflag)
{
  int fl = *dflag;
  uint32_t idx = ((uint32_t)blockIdx.x * 256u + threadIdx.x) * 8u;
  uint32_t c = idx & (CC - 1);
  uint32_t row = idx >> 11;
  uint32_t t = row & (TT - 1);
  float xv[8], pv[8];
  unpack8(*(const uint4*)(xl + idx), xv);
  if (t) { unpack8(*(const uint4*)(xl + idx - CC), pv); }
  else   { for (int j = 0; j < 8; j++) pv[j] = 0.f; }
  const void* tms[4] = { tmr, tmk, tmv, tmg };
  const size_t SL = (size_t)MTOT * CC;
  #pragma unroll
  for (int a = 0; a < 4; a++) {
    float tm[8], o[8];
    load8f(tms[a], c, fl, tm);
    #pragma unroll
    for (int j = 0; j < 8; j++) o[j] = xv[j] * tm[j] + pv[j] * (1.f - tm[j]);
    *(uint4*)(out + a * SL + idx) = pack8(o);
  }
}

__global__ __launch_bounds__(256) void mix2_kernel(const uint16_t* __restrict__ xl,
    const void* __restrict__ tk, const void* __restrict__ tr,
    uint16_t* __restrict__ ok, uint16_t* __restrict__ orr,
    const int* __restrict__ dflag)
{
  int fl = *dflag;
  uint32_t idx = ((uint32_t)blockIdx.x * 256u + threadIdx.x) * 8u;
  uint32_t c = idx & (CC - 1);
  uint32_t row = idx >> 11;
  uint32_t t = row & (TT - 1);
  float xv[8], pv[8], tm[8], o[8];
  unpack8(*(const uint4*)(xl + idx), xv);
  if (t) { unpack8(*(const uint4*)(xl + idx - CC), pv); }
  else   { for (int j = 0; j < 8; j++) pv[j] = 0.f; }
  load8f(tk, c, fl, tm);
  #pragma unroll
  for (int j = 0; j < 8; j++) o[j] = xv[j] * tm[j] + pv[j] * (1.f - tm[j]);
  *(uint4*)(ok + idx) = pack8(o);
  load8f(tr, c, fl, tm);
  #pragma unroll
  for (int j = 0; j < 8; j++) o[j] = xv[j] * tm[j] + pv[j] * (1.f - tm[j]);
  *(uint4*)(orr + idx) = pack8(o);
}

// ---------------- weight transpose: W (Kd x Nd, d_in dtype) -> WT (Nd x Kd, bf16) ----------------
__global__ __launch_bounds__(256) void transpose_kernel(const void* __restrict__ W,
    uint16_t* __restrict__ WT, int Kd, int Nd, const int* __restrict__ dflag)
{
  int fl = *dflag;
  __shared__ __align__(16) uint16_t tile[64][66];
  int n0 = blockIdx.x * 64, k0 = blockIdx.y * 64;
  int tid = threadIdx.x;
  int r = tid >> 3, s = tid & 7;
  #pragma unroll
  for (int p = 0; p < 2; p++) {
    int row = p * 32 + r;
    float tv[8];
    load8f(W, (size_t)(k0 + row) * Nd + n0 + s * 8, fl, tv);
    uint16_t* t = &tile[row][s * 8];
    #pragma unroll
    for (int e = 0; e < 8; e++) t[e] = f2bf(tv[e]);
  }
  __syncthreads();
  #pragma unroll
  for (int p = 0; p < 2; p++) {
    int row = p * 32 + r;  // n index
    uint16_t tmp[8];
    #pragma unroll
    for (int e = 0; e < 8; e++) tmp[e] = tile[s * 8 + e][row];
    uint4 o;
    o.x = (uint32_t)tmp[0] | ((uint32_t)tmp[1] << 16);
    o.y = (uint32_t)tmp[2] | ((uint32_t)tmp[3] << 16);
    o.z = (uint32_t)tmp[4] | ((uint32_t)tmp[5] << 16);
    o.w = (uint32_t)tmp[6] | ((uint32_t)tmp[7] << 16);
    *(uint4*)(WT + (size_t)(n0 + row) * Kd + k0 + s * 8) = o;
  }
}

// ---------------- GEMM: A (M x K, bf16 rm) @ W via WT (N x K, bf16 rm) ----------------
enum { EPI_RESID = 2, EPI_RELU2 = 3, EPI_SIGMOID = 4, EPI_FINAL = 5, EPI_RKVG = 6 };

template<int EPI>
__global__ __launch_bounds__(256, 2) void gemm_kernel(
    const uint16_t* __restrict__ Ain, const uint16_t* __restrict__ BTin,
    void* __restrict__ Cout, int N, int K,
    const void* __restrict__ auxA, const float* __restrict__ auxf,
    const int* __restrict__ dflag)
{
  const uint16_t* A  = Ain;
  const uint16_t* BT = BTin;
  uint16_t* co16 = (uint16_t*)Cout;
  float*    co32 = (float*)Cout;
  int fl = 0;
  if constexpr (EPI == EPI_RESID || EPI == EPI_FINAL) fl = *dflag;
  bool silu = false;
  if constexpr (EPI == EPI_RKVG) {
    int z = blockIdx.z;
    A    += (size_t)z * MTOT * CC;
    BT   += (size_t)z * CC * CC;
    co16 += (size_t)z * MTOT * CC;
    silu = (z == 3);
  }
  int m0 = blockIdx.y * 128, n0 = blockIdx.x * 128;
  __shared__ __align__(16) uint16_t As[128 * 64];
  __shared__ __align__(16) uint16_t Bs[128 * 64];
  int tid = threadIdx.x;
  int lane = tid & 63, wave = tid >> 6;
  int wm = (wave >> 1) * 64, wn = (wave & 1) * 64;
  int l15 = lane & 15, lq = lane >> 4;
  f32x4 acc[4][4];
  #pragma unroll
  for (int i = 0; i < 4; i++)
    #pragma unroll
    for (int j = 0; j < 4; j++) acc[i][j] = 0.f;
  const int rr = tid >> 3, seg = tid & 7;
  const uint16_t* Ag = A + (size_t)(m0 + rr) * K + seg * 8;
  const uint16_t* Bg = BT + (size_t)(n0 + rr) * K + seg * 8;
  uint16_t* Asw = As + tid * 8;
  uint16_t* Bsw = Bs + tid * 8;
  for (int k0 = 0; k0 < K; k0 += 64) {
    __syncthreads();
    #pragma unroll
    for (int p = 0; p < 4; p++) {
      gload_lds16(Ag + (size_t)p * 32 * K + k0, Asw + p * 2048);
      gload_lds16(Bg + (size_t)p * 32 * K + k0, Bsw + p * 2048);
    }
    __syncthreads();
    #pragma unroll
    for (int kk = 0; kk < 2; kk++) {
      int co = kk * 32 + lq * 8;
      bf16x8 af[4], bv[4];
      #pragma unroll
      for (int f = 0; f < 4; f++) af[f] = *(const bf16x8*)&As[(wm + f * 16 + l15) * 64 + co];
      #pragma unroll
      for (int f = 0; f < 4; f++) bv[f] = *(const bf16x8*)&Bs[(wn + f * 16 + l15) * 64 + co];
      #pragma unroll
      for (int fm = 0; fm < 4; fm++)
        #pragma unroll
        for (int fn = 0; fn < 4; fn++)
          acc[fm][fn] = __builtin_amdgcn_mfma_f32_16x16x32_bf16(af[fm], bv[fn], acc[fm][fn], 0, 0, 0);
    }
  }
  #pragma unroll
  for (int fm = 0; fm < 4; fm++) {
    #pragma unroll
    for (int q = 0; q < 4; q++) {
      int gr = m0 + wm + fm * 16 + lq * 4 + q;
      size_t rowb = (size_t)gr * N;
      #pragma unroll
      for (int fn = 0; fn < 4; fn++) {
        int gc = n0 + wn + fn * 16 + l15;
        size_t idx = rowb + gc;
        float val = acc[fm][fn][q];
        if constexpr (EPI == EPI_RKVG) {
          if (silu) val = val / (1.f + __expf(-fmaxf(val, -80.f)));
          co16[idx] = f2bf(val);
        } else if constexpr (EPI == EPI_RESID) {
          co32[idx] = val + load1f(auxA, idx, fl);
        } else if constexpr (EPI == EPI_RELU2) {
          float t = fmaxf(val, 0.f);
          co16[idx] = f2bf(t * t);
        } else if constexpr (EPI == EPI_SIGMOID) {
          co16[idx] = f2bf(1.f / (1.f + __expf(-val)));
        } else if constexpr (EPI == EPI_FINAL) {
          float res = auxf[idx] + bf2f(((const uint16_t*)auxA)[idx]) * val;
          if (fl) co32[idx] = res; else co16[idx] = f2bf(res);
        }
      }
    }
  }
}

// ---------------- WKV5 chunked ----------------
__global__ __launch_bounds__(256) void wkv_p_kernel(
    const uint16_t* __restrict__ kq, const uint16_t* __restrict__ vq,
    const void* __restrict__ wq, float* __restrict__ P,
    const int* __restrict__ dflag)
{
  int fl = *dflag;
  int blk = blockIdx.x;
  int c = blk & 15, h = (blk >> 4) & 31, b = blk >> 9;
  __shared__ __align__(16) float Kt[64][64];
  __shared__ __align__(16) uint16_t Vb[64][64];
  __shared__ __align__(16) float e_s[64];
  int tid = threadIdx.x;
  if (tid < 64) e_s[tid] = fminf(__expf(load1f(wq, h * 64 + tid, fl)), 100.f);
  __syncthreads();
  int rr = tid >> 3, cs = (tid & 7) * 8;
  #pragma unroll
  for (int p = 0; p < 2; p++) {
    int s = p * 32 + rr;
    size_t gbase = ((size_t)(b * TT + c * 64 + s)) * CC + h * 64 + cs;
    float k8[8];
    unpack8(*(const uint4*)(kq + gbase), k8);
    float sp = (float)(s + 1) * LOG2E;
    #pragma unroll
    for (int j = 0; j < 8; j++) Kt[s][cs + j] = k8[j] * exp2f(fminf(sp * e_s[cs + j], 80.f));
    *(uint4*)&Vb[s][cs] = *(const uint4*)(vq + gbase);
  }
  __syncthreads();
  int tx = tid & 15, ty = tid >> 4;
  int i0 = ty * 4, j0 = tx * 4;
  float acc[4][4] = {};
  for (int s = 0; s < 64; s++) {
    float4 a = *(const float4*)&Kt[s][i0];
    ushort4 vv = *(const ushort4*)&Vb[s][j0];
    float b0 = bf2f(vv.x), b1 = bf2f(vv.y), b2 = bf2f(vv.z), b3 = bf2f(vv.w);
    float am[4] = { a.x, a.y, a.z, a.w };
    #pragma unroll
    for (int m = 0; m < 4; m++) {
      acc[m][0] += am[m] * b0; acc[m][1] += am[m] * b1;
      acc[m][2] += am[m] * b2; acc[m][3] += am[m] * b3;
    }
  }
  float* Pb = P + (size_t)blk * 4096;
  #pragma unroll
  for (int m = 0; m < 4; m++) {
    float dl = exp2f(-64.0f * LOG2E * e_s[i0 + m]);
    float4 o = { acc[m][0] * dl, acc[m][1] * dl, acc[m][2] * dl, acc[m][3] * dl };
    *(float4*)&Pb[(i0 + m) * 64 + j0] = o;
  }
}

__global__ __launch_bounds__(256) void wkv_s_kernel(const float* __restrict__ P,
    const void* __restrict__ wq, float* __restrict__ S,
    const int* __restrict__ dflag)
{
  int fl = *dflag;
  int bh = blockIdx.x;           // b*32+h
  int h = bh & 31;
  int tid = threadIdx.x;
  int i = tid >> 2, q = tid & 3;
  float e = fminf(__expf(load1f(wq, h * 64 + i, fl)), 100.f);
  float dl = exp2f(-64.0f * LOG2E * e);
  float4 s0 = {0,0,0,0}, s1 = {0,0,0,0}, s2 = {0,0,0,0}, s3 = {0,0,0,0};
  for (int c = 0; c < 16; c++) {
    size_t base = ((size_t)bh * 16 + c) * 4096 + (size_t)i * 64 + q * 16;
    *(float4*)&S[base + 0]  = s0;
    *(float4*)&S[base + 4]  = s1;
    *(float4*)&S[base + 8]  = s2;
    *(float4*)&S[base + 12] = s3;
    float4 p0 = *(const float4*)&P[base + 0];
    float4 p1 = *(const float4*)&P[base + 4];
    float4 p2 = *(const float4*)&P[base + 8];
    float4 p3 = *(const float4*)&P[base + 12];
    s0 = make_float4(dl * s0.x + p0.x, dl * s0.y + p0.y, dl * s0.z + p0.z, dl * s0.w + p0.w);
    s1 = make_float4(dl * s1.x + p1.x, dl * s1.y + p1.y, dl * s1.z + p1.z, dl * s1.w + p1.w);
    s2 = make_float4(dl * s2.x + p2.x, dl * s2.y + p2.y, dl * s2.z + p2.z, dl * s2.w + p2.w);
    s3 = make_float4(dl * s3.x + p3.x, dl * s3.y + p3.y, dl * s3.z + p3.z, dl * s3.w + p3.w);
  }
}

__global__ __launch_bounds__(256, 2) void wkv_y_kernel(
    const uint16_t* __restrict__ rq, const uint16_t* __restrict__ kq,
    const uint16_t* __restrict__ vq, const void* __restrict__ wq,
    const void* __restrict__ uq, const float* __restrict__ S,
    float* __restrict__ att, const int* __restrict__ dflag)
{
  int fl = *dflag;
  int blk = blockIdx.x;
  int c = blk & 15, h = (blk >> 4) & 31, b = blk >> 9;
  __shared__ __align__(16) float Rt[64][64];
  __shared__ __align__(16) float Kt[64][64];   // later holds A
  __shared__ __align__(16) uint16_t Vb[64][64];
  __shared__ __align__(16) float Ss[64][64];
  __shared__ __align__(16) float e_s[64];
  __shared__ __align__(16) float ud_s[64];
  int tid = threadIdx.x;
  if (tid < 64) {
    float e = fminf(__expf(load1f(wq, h * 64 + tid, fl)), 100.f);
    e_s[tid] = e;
    ud_s[tid] = load1f(uq, h * 64 + tid, fl) * __expf(-e);
  }
  __syncthreads();
  int rr = tid >> 3, cs = (tid & 7) * 8;
  #pragma unroll
  for (int p = 0; p < 2; p++) {
    int s = p * 32 + rr;
    size_t gbase = ((size_t)(b * TT + c * 64 + s)) * CC + h * 64 + cs;
    float r8[8], k8[8];
    unpack8(*(const uint4*)(rq + gbase), r8);
    unpack8(*(const uint4*)(kq + gbase), k8);
    float tneg = -(float)s * LOG2E;
    float spos = (float)(s + 1) * LOG2E;
    #pragma unroll
    for (int j = 0; j < 8; j++) {
      float e = e_s[cs + j];
      Rt[s][cs + j] = r8[j] * exp2f(tneg * e);
      Kt[s][cs + j] = k8[j] * exp2f(fminf(spos * e, 80.f));
    }
    *(uint4*)&Vb[s][cs] = *(const uint4*)(vq + gbase);
  }
  {
    int r2 = tid >> 2, q = tid & 3;
    const float* Sbp = S + (size_t)blk * 4096 + (size_t)r2 * 64 + q * 16;
    *(float4*)&Ss[r2][q * 16 + 0]  = *(const float4*)&Sbp[0];
    *(float4*)&Ss[r2][q * 16 + 4]  = *(const float4*)&Sbp[4];
    *(float4*)&Ss[r2][q * 16 + 8]  = *(const float4*)&Sbp[8];
    *(float4*)&Ss[r2][q * 16 + 12] = *(const float4*)&Sbp[12];
  }
  __syncthreads();
  int tx = tid & 15, ty = tid >> 4;
  int t0 = ty * 4, s0 = tx * 4;
  float acc[4][4] = {};
  for (int iq = 0; iq < 16; iq++) {
    int i = iq * 4;
    float4 ra[4], kb[4];
    #pragma unroll
    for (int m = 0; m < 4; m++) ra[m] = *(const float4*)&Rt[t0 + m][i];
    #pragma unroll
    for (int n = 0; n < 4; n++) kb[n] = *(const float4*)&Kt[s0 + n][i];
    #pragma unroll
    for (int m = 0; m < 4; m++)
      #pragma unroll
      for (int n = 0; n < 4; n++)
        acc[m][n] += ra[m].x * kb[n].x + ra[m].y * kb[n].y + ra[m].z * kb[n].z + ra[m].w * kb[n].w;
  }
  float dg = 0.f;
  if (tid < 64) {
    for (int iq = 0; iq < 16; iq++) {
      int i = iq * 4;
      float4 a = *(const float4*)&Rt[tid][i];
      float4 kk = *(const float4*)&Kt[tid][i];
      float4 u4 = *(const float4*)&ud_s[i];
      dg += a.x * kk.x * u4.x + a.y * kk.y * u4.y + a.z * kk.z * u4.z + a.w * kk.w * u4.w;
    }
  }
  __syncthreads();
  #pragma unroll
  for (int m = 0; m < 4; m++)
    #pragma unroll
    for (int n = 0; n < 4; n++) {
      int t = t0 + m, s = s0 + n;
      Kt[t][s] = (s < t) ? acc[m][n] : 0.0f;
    }
  __syncthreads();
  if (tid < 64) Kt[tid][tid] = dg;
  __syncthreads();
  int j0 = tx * 4;
  float y[4][4] = {};
  for (int sq = 0; sq < 16; sq++) {
    int s = sq * 4;
    float4 a4[4];
    #pragma unroll
    for (int m = 0; m < 4; m++) a4[m] = *(const float4*)&Kt[t0 + m][s];
    float vb[4][4];
    #pragma unroll
    for (int qq = 0; qq < 4; qq++) {
      ushort4 vv = *(const ushort4*)&Vb[s + qq][j0];
      vb[qq][0] = bf2f(vv.x); vb[qq][1] = bf2f(vv.y); vb[qq][2] = bf2f(vv.z); vb[qq][3] = bf2f(vv.w);
    }
    #pragma unroll
    for (int m = 0; m < 4; m++)
      #pragma unroll
      for (int n = 0; n < 4; n++)
        y[m][n] += a4[m].x * vb[0][n] + a4[m].y * vb[1][n] + a4[m].z * vb[2][n] + a4[m].w * vb[3][n];
  }
  for (int iq = 0; iq < 16; iq++) {
    int i = iq * 4;
    float4 r4[4], s4[4];
    #pragma unroll
    for (int m = 0; m < 4; m++) r4[m] = *(const float4*)&Rt[t0 + m][i];
    #pragma unroll
    for (int qq = 0; qq < 4; qq++) s4[qq] = *(const float4*)&Ss[i + qq][j0];
    #pragma unroll
    for (int m = 0; m < 4; m++)
      #pragma unroll
      for (int n = 0; n < 4; n++)
        y[m][n] += r4[m].x * s4[0][n] + r4[m].y * s4[1][n] + r4[m].z * s4[2][n] + r4[m].w * s4[3][n];
  }
  #pragma unroll
  for (int m = 0; m < 4; m++) {
    size_t ob = ((size_t)(b * TT + c * 64 + t0 + m)) * CC + h * 64 + j0;
    *(float4*)&att[ob] = make_float4(y[m][0], y[m][1], y[m][2], y[m][3]);
  }
}

// ---------------- GroupNorm(att/8) * g ----------------
__global__ __launch_bounds__(256) void gn_mul_kernel(const float* __restrict__ att,
    const void* __restrict__ gg, const void* __restrict__ bb,
    const uint16_t* __restrict__ gate, uint16_t* __restrict__ out,
    const int* __restrict__ dflag)
{
  int fl = *dflag;
  int row = blockIdx.x;
  int tid = threadIdx.x;
  size_t base = (size_t)row * CC + (size_t)tid * 8;
  float4 a0 = *(const float4*)(att + base);
  float4 a1 = *(const float4*)(att + base + 4);
  float v[8] = { a0.x, a0.y, a0.z, a0.w, a1.x, a1.y, a1.z, a1.w };
  #pragma unroll
  for (int j = 0; j < 8; j++) v[j] *= 0.125f;
  float s = 0.f, s2 = 0.f;
  #pragma unroll
  for (int j = 0; j < 8; j++) { s += v[j]; s2 += v[j] * v[j]; }
  s += __shfl_xor(s, 1); s += __shfl_xor(s, 2); s += __shfl_xor(s, 4);
  s2 += __shfl_xor(s2, 1); s2 += __shfl_xor(s2, 2); s2 += __shfl_xor(s2, 4);
  float m = s * (1.f / 64.f);
  float var = s2 * (1.f / 64.f) - m * m;
  float rstd = rsqrtf(fmaxf(var, 0.f) + LNEPS);
  int c = tid * 8;
  float g8[8], b8[8], gt8[8], o[8];
  load8f(gg, c, fl, g8);
  load8f(bb, c, fl, b8);
  unpack8(*(const uint4*)(gate + base), gt8);
  #pragma unroll
  for (int j = 0; j < 8; j++) o[j] = ((v[j] - m) * rstd * g8[j] + b8[j]) * gt8[j];
  *(uint4*)(out + base) = pack8(o);
}

// ---------------- launch ----------------
extern "C" void kernel_launch(void* const* d_in, const int* in_sizes, int n_in,
                              void* d_out, int out_size, void* d_ws, size_t ws_size,
                              hipStream_t stream)
{
  const void* x    = d_in[0];
  const void* ln1g = d_in[1];
  const void* ln1b = d_in[2];
  const void* ln2g = d_in[3];
  const void* ln2b = d_in[4];
  const void* tmk  = d_in[5];
  const void* tmv  = d_in[6];
  const void* tmr  = d_in[7];
  const void* tmg  = d_in[8];
  const void* tdec = d_in[9];
  const void* tfaa = d_in[10];
  const void* Wr   = d_in[11];
  const void* Wk   = d_in[12];
  const void* Wv   = d_in[13];
  const void* Wg   = d_in[14];
  const void* Wo   = d_in[15];
  const void* lnxg = d_in[16];
  const void* lnxb = d_in[17];
  const void* fmk  = d_in[18];
  const void* fmr  = d_in[19];
  const void* Wkey = d_in[20];
  const void* Wrec = d_in[21];
  const void* Wval = d_in[22];

  char* ws = (char*)d_ws;
  const size_t SL  = (size_t)MTOT * CC;   // 4,194,304 elems
  const size_t SLW = (size_t)CC * CC;
  uint16_t* XL   = (uint16_t*)(ws + 0);            // 8 MiB (reused for XL2)
  uint16_t* MIX4 = (uint16_t*)(ws + 8388608);      // 32 MiB
  uint16_t* RKVG = (uint16_t*)(ws + 41943040);     // 32 MiB
  float*    ATT  = (float*)   (ws + 75497472);     // 16 MiB (aliased as X1)
  float*    X1   = ATT;
  float*    Pb   = (float*)   (ws + 92274688);     // 16 MiB
  float*    Sb   = (float*)   (ws + 109051904);    // 16 MiB
  uint16_t* KK   = (uint16_t*)(ws + 92274688);     // 32 MiB, alias P+S (dead)
  uint16_t* WT   = (uint16_t*)(ws + 125829120);    // 32 MiB
  int*      FLAG = (int*)     (ws + 159383552);
  (void)in_sizes; (void)n_in; (void)out_size; (void)ws_size;

  // 0. dtype probe
  probe_kernel<<<dim3(1), 64, 0, stream>>>((const uint16_t*)x, FLAG);
  // 1. LN1
  ln_kernel<0><<<dim3(MTOT), 256, 0, stream>>>(x, ln1g, ln1b, XL, FLAG);
  // transposes Wr,Wk,Wv,Wg -> WT slots 0..3
  transpose_kernel<<<dim3(32, 32), 256, 0, stream>>>(Wr, WT + 0 * SLW, CC, CC, FLAG);
  transpose_kernel<<<dim3(32, 32), 256, 0, stream>>>(Wk, WT + 1 * SLW, CC, CC, FLAG);
  transpose_kernel<<<dim3(32, 32), 256, 0, stream>>>(Wv, WT + 2 * SLW, CC, CC, FLAG);
  transpose_kernel<<<dim3(32, 32), 256, 0, stream>>>(Wg, WT + 3 * SLW, CC, CC, FLAG);
  // 2. mixes (slices r,k,v,g)
  mix4_kernel<<<dim3(2048), 256, 0, stream>>>(XL, tmr, tmk, tmv, tmg, MIX4, FLAG);
  // 3. batched GEMM: r,k,v,g (silu on g)
  gemm_kernel<EPI_RKVG><<<dim3(16, 16, 4), 256, 0, stream>>>(MIX4, WT, (void*)RKVG, CC, CC, nullptr, nullptr, FLAG);
  // 4. WKV5 chunked
  wkv_p_kernel<<<dim3(1024), 256, 0, stream>>>(RKVG + 1 * SL, RKVG + 2 * SL, tdec, Pb, FLAG);
  wkv_s_kernel<<<dim3(64), 256, 0, stream>>>(Pb, tdec, Sb, FLAG);
  wkv_y_kernel<<<dim3(1024), 256, 0, stream>>>(RKVG + 0 * SL, RKVG + 1 * SL, RKVG + 2 * SL, tdec, tfaa, Sb, ATT, FLAG);
  // 5. GroupNorm(att/8)*g -> MIX4 slot0
  gn_mul_kernel<<<dim3(MTOT), 256, 0, stream>>>(ATT, lnxg, lnxb, RKVG + 3 * SL, MIX4, FLAG);
  // 6. Wo GEMM + residual -> X1 (f32)
  transpose_kernel<<<dim3(32, 32), 256, 0, stream>>>(Wo, WT, CC, CC, FLAG);
  gemm_kernel<EPI_RESID><<<dim3(16, 16), 256, 0, stream>>>(MIX4, WT, (void*)X1, CC, CC, x, nullptr, FLAG);
  // 7. LN2 -> XL (reuse)
  ln_kernel<1><<<dim3(MTOT), 256, 0, stream>>>(X1, ln2g, ln2b, XL, FLAG);
  // 8. mixes ck (MIX4 slot0), cr (RKVG slot0)
  mix2_kernel<<<dim3(2048), 256, 0, stream>>>(XL, fmk, fmr, MIX4, RKVG, FLAG);
  // 9. Wkey GEMM -> kk = relu(ck@Wkey)^2
  transpose_kernel<<<dim3(FFD / 64, CC / 64), 256, 0, stream>>>(Wkey, WT, CC, FFD, FLAG);
  gemm_kernel<EPI_RELU2><<<dim3(FFD / 128, 16), 256, 0, stream>>>(MIX4, WT, (void*)KK, FFD, CC, nullptr, nullptr, FLAG);
  // 10. Wrec GEMM -> sr = sigmoid(cr@Wrec)
  transpose_kernel<<<dim3(32, 32), 256, 0, stream>>>(Wrec, WT, CC, CC, FLAG);
  gemm_kernel<EPI_SIGMOID><<<dim3(16, 16), 256, 0, stream>>>(RKVG, WT, (void*)(RKVG + 2 * SL), CC, CC, nullptr, nullptr, FLAG);
  // 11. Wval GEMM -> out = X1 + sr * (kk@Wval)
  transpose_kernel<<<dim3(CC / 64, FFD / 64), 256, 0, stream>>>(Wval, WT, FFD, CC, FLAG);
  gemm_kernel<EPI_FINAL><<<dim3(16, 16), 256, 0, stream>>>(KK, WT, d_out, CC, FFD, RKVG + 2 * SL, X1, FLAG);
}

// Round 3
// 728.677 us; speedup vs baseline: 1.2159x; 1.2159x over previous
//
#include <hip/hip_runtime.h>
#include <stdint.h>

#define BB 2
#define TT 1024
#define CC 2048
#define HH 32
#define NNH 64
#define FFD 8192
#define MTOT (BB*TT)    // 2048 rows
#define LNEPS 1e-5f
#define LOG2E 1.44269504088896340736f

typedef __attribute__((ext_vector_type(8))) __bf16 bf16x8;
typedef __attribute__((ext_vector_type(4))) float f32x4;

#define USE_GLL 1
typedef __attribute__((address_space(1))) void GAS;
typedef __attribute__((address_space(3))) void LAS;

__device__ inline void gload_lds16(const uint16_t* g, uint16_t* l) {
#if USE_GLL
  __builtin_amdgcn_global_load_lds((GAS*)g, (LAS*)l, 16, 0, 0);
#else
  *(uint4*)l = *(const uint4*)g;
#endif
}

__device__ inline float bf2f(uint32_t u) {
  union { uint32_t i; float f; } v; v.i = u << 16; return v.f;
}
__device__ inline uint16_t f2bf(float f) {
  union { float f; uint32_t i; } v; v.f = f;
  uint32_t r = v.i + 0x7FFFu + ((v.i >> 16) & 1u);
  return (uint16_t)(r >> 16);
}
__device__ inline void unpack8(uint4 d, float* v) {
  v[0] = bf2f(d.x & 0xffffu); v[1] = bf2f(d.x >> 16);
  v[2] = bf2f(d.y & 0xffffu); v[3] = bf2f(d.y >> 16);
  v[4] = bf2f(d.z & 0xffffu); v[5] = bf2f(d.z >> 16);
  v[6] = bf2f(d.w & 0xffffu); v[7] = bf2f(d.w >> 16);
}
__device__ inline uint4 pack8(const float* v) {
  uint4 d;
  d.x = (uint32_t)f2bf(v[0]) | ((uint32_t)f2bf(v[1]) << 16);
  d.y = (uint32_t)f2bf(v[2]) | ((uint32_t)f2bf(v[3]) << 16);
  d.z = (uint32_t)f2bf(v[4]) | ((uint32_t)f2bf(v[5]) << 16);
  d.w = (uint32_t)f2bf(v[6]) | ((uint32_t)f2bf(v[7]) << 16);
  return d;
}

// flag-aware loads for d_in buffers (fl=1 -> fp32, fl=0 -> bf16)
__device__ inline void load8f(const void* p, size_t idx, int fl, float* v) {
  if (fl) {
    const float* q = (const float*)p + idx;
    float4 a = *(const float4*)q; float4 b = *(const float4*)(q + 4);
    v[0]=a.x; v[1]=a.y; v[2]=a.z; v[3]=a.w; v[4]=b.x; v[5]=b.y; v[6]=b.z; v[7]=b.w;
  } else {
    unpack8(*(const uint4*)((const uint16_t*)p + idx), v);
  }
}
__device__ inline float load1f(const void* p, size_t idx, int fl) {
  return fl ? ((const float*)p)[idx] : bf2f(((const uint16_t*)p)[idx]);
}

// ---------------- dtype probe ----------------
__global__ void probe_kernel(const uint16_t* __restrict__ x, int* __restrict__ flag) {
  int tid = threadIdx.x; // 64
  float m = 0.f;
  for (int i = tid; i < 4096; i += 64) {
    float a = fabsf(bf2f(x[i]));
    if (a > m) m = a;
  }
  for (int o = 32; o; o >>= 1) { float t = __shfl_down(m, o); if (t > m) m = t; }
  if (tid == 0) *flag = (m > 1e6f) ? 1 : 0;
}

// ---------------- LayerNorm ----------------
template<int INMODE>
__global__ __launch_bounds__(256) void ln_kernel(const void* __restrict__ x,
    const void* __restrict__ g, const void* __restrict__ b,
    uint16_t* __restrict__ out, const int* __restrict__ dflag)
{
  int fl = *dflag;
  int row = blockIdx.x;
  int tid = threadIdx.x;
  int lane = tid & 63, wave = tid >> 6;
  size_t base = (size_t)row * CC + (size_t)tid * 8;
  float v[8];
  if constexpr (INMODE == 1) {
    const float* q = (const float*)x + base;
    float4 a = *(const float4*)q; float4 c = *(const float4*)(q + 4);
    v[0]=a.x; v[1]=a.y; v[2]=a.z; v[3]=a.w; v[4]=c.x; v[5]=c.y; v[6]=c.z; v[7]=c.w;
  } else {
    load8f(x, base, fl, v);
  }
  float s = 0.f, s2 = 0.f;
  #pragma unroll
  for (int j = 0; j < 8; j++) { s += v[j]; s2 += v[j] * v[j]; }
  for (int o = 32; o; o >>= 1) { s += __shfl_down(s, o); s2 += __shfl_down(s2, o); }
  __shared__ float red[8];
  if (lane == 0) { red[wave] = s; red[wave + 4] = s2; }
  __syncthreads();
  s  = red[0] + red[1] + red[2] + red[3];
  s2 = red[4] + red[5] + red[6] + red[7];
  float mean = s * (1.0f / CC);
  float var  = s2 * (1.0f / CC) - mean * mean;
  float rstd = rsqrtf(fmaxf(var, 0.f) + LNEPS);
  float gj[8], bj[8];
  load8f(g, (size_t)tid * 8, fl, gj);
  load8f(b, (size_t)tid * 8, fl, bj);
  float o8[8];
  #pragma unroll
  for (int j = 0; j < 8; j++) o8[j] = (v[j] - mean) * rstd * gj[j] + bj[j];
  *(uint4*)(out + base) = pack8(o8);
}

// ---------------- time-shift mixes ----------------
__global__ __launch_bounds__(256) void mix4_kernel(const uint16_t* __restrict__ xl,
    const void* __restrict__ tmr, const void* __restrict__ tmk,
    const void* __restrict__ tmv, const void* __restrict__ tmg,
    uint16_t* __restrict__ out, const int* __restrict__ dflag)
{
  int fl = *dflag;
  uint32_t idx = ((uint32_t)blockIdx.x * 256u + threadIdx.x) * 8u;
  uint32_t c = idx & (CC - 1);
  uint32_t row = idx >> 11;
  uint32_t t = row & (TT - 1);
  float xv[8], pv[8];
  unpack8(*(const uint4*)(xl + idx), xv);
  if (t) { unpack8(*(const uint4*)(xl + idx - CC), pv); }
  else   { for (int j = 0; j < 8; j++) pv[j] = 0.f; }
  const void* tms[4] = { tmr, tmk, tmv, tmg };
  const size_t SL = (size_t)MTOT * CC;
  #pragma unroll
  for (int a = 0; a < 4; a++) {
    float tm[8], o[8];
    load8f(tms[a], c, fl, tm);
    #pragma unroll
    for (int j = 0; j < 8; j++) o[j] = xv[j] * tm[j] + pv[j] * (1.f - tm[j]);
    *(uint4*)(out + a * SL + idx) = pack8(o);
  }
}

__global__ __launch_bounds__(256) void mix2_kernel(const uint16_t* __restrict__ xl,
    const void* __restrict__ tk, const void* __restrict__ tr,
    uint16_t* __restrict__ ok, uint16_t* __restrict__ orr,
    const int* __restrict__ dflag)
{
  int fl = *dflag;
  uint32_t idx = ((uint32_t)blockIdx.x * 256u + threadIdx.x) * 8u;
  uint32_t c = idx & (CC - 1);
  uint32_t row = idx >> 11;
  uint32_t t = row & (TT - 1);
  float xv[8], pv[8], tm[8], o[8];
  unpack8(*(const uint4*)(xl + idx), xv);
  if (t) { unpack8(*(const uint4*)(xl + idx - CC), pv); }
  else   { for (int j = 0; j < 8; j++) pv[j] = 0.f; }
  load8f(tk, c, fl, tm);
  #pragma unroll
  for (int j = 0; j < 8; j++) o[j] = xv[j] * tm[j] + pv[j] * (1.f - tm[j]);
  *(uint4*)(ok + idx) = pack8(o);
  load8f(tr, c, fl, tm);
  #pragma unroll
  for (int j = 0; j < 8; j++) o[j] = xv[j] * tm[j] + pv[j] * (1.f - tm[j]);
  *(uint4*)(orr + idx) = pack8(o);
}

// ---------------- weight transpose: W (Kd x Nd, d_in dtype) -> WT (Nd x Kd, bf16) ----------------
__device__ inline void transpose_tile(const void* W, uint16_t* WT, int Kd, int Nd,
                                      int n0, int k0, int fl, int tid)
{
  __shared__ __align__(16) uint16_t tile[64][66];
  int r = tid >> 3, s = tid & 7;
  #pragma unroll
  for (int p = 0; p < 2; p++) {
    int row = p * 32 + r;
    float tv[8];
    load8f(W, (size_t)(k0 + row) * Nd + n0 + s * 8, fl, tv);
    uint16_t* t = &tile[row][s * 8];
    #pragma unroll
    for (int e = 0; e < 8; e++) t[e] = f2bf(tv[e]);
  }
  __syncthreads();
  #pragma unroll
  for (int p = 0; p < 2; p++) {
    int row = p * 32 + r;
    uint16_t tmp[8];
    #pragma unroll
    for (int e = 0; e < 8; e++) tmp[e] = tile[s * 8 + e][row];
    uint4 o;
    o.x = (uint32_t)tmp[0] | ((uint32_t)tmp[1] << 16);
    o.y = (uint32_t)tmp[2] | ((uint32_t)tmp[3] << 16);
    o.z = (uint32_t)tmp[4] | ((uint32_t)tmp[5] << 16);
    o.w = (uint32_t)tmp[6] | ((uint32_t)tmp[7] << 16);
    *(uint4*)(WT + (size_t)(n0 + row) * Kd + k0 + s * 8) = o;
  }
}

__global__ __launch_bounds__(256) void transpose_kernel(const void* __restrict__ W,
    uint16_t* __restrict__ WT, int Kd, int Nd, const int* __restrict__ dflag)
{
  transpose_tile(W, WT, Kd, Nd, blockIdx.x * 64, blockIdx.y * 64, *dflag, threadIdx.x);
}

// 4 square CCxCC transposes in one launch (z selects)
__global__ __launch_bounds__(256) void transpose4_kernel(
    const void* __restrict__ W0, const void* __restrict__ W1,
    const void* __restrict__ W2, const void* __restrict__ W3,
    uint16_t* __restrict__ WT, const int* __restrict__ dflag)
{
  const void* Ws[4] = { W0, W1, W2, W3 };
  int z = blockIdx.z;
  transpose_tile(Ws[z], WT + (size_t)z * CC * CC, CC, CC,
                 blockIdx.x * 64, blockIdx.y * 64, *dflag, threadIdx.x);
}

// ---------------- GEMM with XOR-swizzled LDS ----------------
// LDS slot (row, g_store) holds global k-group g_store ^ (row&7); staging lanes
// permute their global source within the same 128B segment (coalescing intact).
enum { EPI_RESID = 2, EPI_RKVG = 6, EPI_FF2 = 7, EPI_PART = 8 };

template<int EPI>
__global__ __launch_bounds__(256, 2) void gemm_kernel(
    const uint16_t* __restrict__ Ain, const uint16_t* __restrict__ BTin,
    void* __restrict__ Cout, int N, int Kstride, int Kloop,
    const void* __restrict__ auxA, const float* __restrict__ auxf,
    const uint16_t* __restrict__ A2in, const uint16_t* __restrict__ BT2in,
    void* __restrict__ C2out, const int* __restrict__ dflag)
{
  const uint16_t* A  = Ain;
  const uint16_t* BT = BTin;
  uint16_t* co16 = (uint16_t*)Cout;
  float*    co32 = (float*)Cout;
  int fl = 0;
  if constexpr (EPI == EPI_RESID) fl = *dflag;
  bool silu = false, sigm = false;
  int bx = blockIdx.x;
  int N_ = N;
  int n0 = bx * 128;
  if constexpr (EPI == EPI_RKVG) {
    int z = blockIdx.z;
    A    += (size_t)z * MTOT * CC;
    BT   += (size_t)z * CC * CC;
    co16 += (size_t)z * MTOT * CC;
    silu = (z == 3);
  }
  if constexpr (EPI == EPI_PART) {
    int z = blockIdx.z;
    A    += (size_t)z * Kloop;      // column offset into K
    BT   += (size_t)z * Kloop;
    co32 += (size_t)z * MTOT * 2048;
  }
  if constexpr (EPI == EPI_FF2) {
    if (bx >= 64) {                  // SIGMOID half: cr @ Wrec
      n0 = (bx - 64) * 128;
      A = A2in; BT = BT2in; co16 = (uint16_t*)C2out; N_ = 2048; sigm = true;
    }
  }
  int m0 = blockIdx.y * 128;
  __shared__ __align__(16) uint16_t As[128 * 64];
  __shared__ __align__(16) uint16_t Bs[128 * 64];
  int tid = threadIdx.x;
  int lane = tid & 63, wave = tid >> 6;
  int wm = (wave >> 1) * 64, wn = (wave & 1) * 64;
  int l15 = lane & 15, lq = lane >> 4;
  int sw = l15 & 7;
  f32x4 acc[4][4];
  #pragma unroll
  for (int i = 0; i < 4; i++)
    #pragma unroll
    for (int j = 0; j < 4; j++) acc[i][j] = 0.f;
  const int rr = tid >> 3, seg = tid & 7;
  const int sseg = (seg ^ (rr & 7)) * 8;   // swizzled k-group source
  const uint16_t* Ag = A + (size_t)(m0 + rr) * Kstride + sseg;
  const uint16_t* Bg = BT + (size_t)(n0 + rr) * Kstride + sseg;
  uint16_t* Asw = As + tid * 8;
  uint16_t* Bsw = Bs + tid * 8;
  for (int k0 = 0; k0 < Kloop; k0 += 64) {
    __syncthreads();
    #pragma unroll
    for (int p = 0; p < 4; p++) {
      gload_lds16(Ag + (size_t)p * 32 * Kstride + k0, Asw + p * 2048);
      gload_lds16(Bg + (size_t)p * 32 * Kstride + k0, Bsw + p * 2048);
    }
    __syncthreads();
    #pragma unroll
    for (int kk = 0; kk < 2; kk++) {
      int cidx = ((kk * 4 + lq) ^ sw) * 8;
      bf16x8 af[4], bv[4];
      #pragma unroll
      for (int f = 0; f < 4; f++) af[f] = *(const bf16x8*)&As[(wm + f * 16 + l15) * 64 + cidx];
      #pragma unroll
      for (int f = 0; f < 4; f++) bv[f] = *(const bf16x8*)&Bs[(wn + f * 16 + l15) * 64 + cidx];
      #pragma unroll
      for (int fm = 0; fm < 4; fm++)
        #pragma unroll
        for (int fn = 0; fn < 4; fn++)
          acc[fm][fn] = __builtin_amdgcn_mfma_f32_16x16x32_bf16(af[fm], bv[fn], acc[fm][fn], 0, 0, 0);
    }
  }
  #pragma unroll
  for (int fm = 0; fm < 4; fm++) {
    #pragma unroll
    for (int q = 0; q < 4; q++) {
      int gr = m0 + wm + fm * 16 + lq * 4 + q;
      size_t rowb = (size_t)gr * N_;
      #pragma unroll
      for (int fn = 0; fn < 4; fn++) {
        int gc = n0 + wn + fn * 16 + l15;
        size_t idx = rowb + gc;
        float val = acc[fm][fn][q];
        if constexpr (EPI == EPI_RKVG) {
          if (silu) val = val / (1.f + __expf(-fmaxf(val, -80.f)));
          co16[idx] = f2bf(val);
        } else if constexpr (EPI == EPI_RESID) {
          co32[idx] = val + load1f(auxA, idx, fl);
        } else if constexpr (EPI == EPI_FF2) {
          if (sigm) {
            co16[idx] = f2bf(1.f / (1.f + __expf(-val)));
          } else {
            float t = fmaxf(val, 0.f);
            co16[idx] = f2bf(t * t);
          }
        } else if constexpr (EPI == EPI_PART) {
          co32[idx] = val;
        }
      }
    }
  }
}

// ---------------- split-K reduce + final epilogue ----------------
__global__ __launch_bounds__(256) void final_reduce_kernel(
    const float* __restrict__ P, const float* __restrict__ x1,
    const uint16_t* __restrict__ sr, void* __restrict__ out,
    const int* __restrict__ dflag)
{
  int fl = *dflag;
  size_t idx = ((size_t)blockIdx.x * 256 + threadIdx.x) * 8;
  const float* P1 = P + (size_t)MTOT * 2048;
  float a[8], b[8], xv[8], s8[8], o[8];
  { float4 t0 = *(const float4*)(P + idx);  float4 t1 = *(const float4*)(P + idx + 4);
    a[0]=t0.x;a[1]=t0.y;a[2]=t0.z;a[3]=t0.w;a[4]=t1.x;a[5]=t1.y;a[6]=t1.z;a[7]=t1.w; }
  { float4 t0 = *(const float4*)(P1 + idx); float4 t1 = *(const float4*)(P1 + idx + 4);
    b[0]=t0.x;b[1]=t0.y;b[2]=t0.z;b[3]=t0.w;b[4]=t1.x;b[5]=t1.y;b[6]=t1.z;b[7]=t1.w; }
  { float4 t0 = *(const float4*)(x1 + idx); float4 t1 = *(const float4*)(x1 + idx + 4);
    xv[0]=t0.x;xv[1]=t0.y;xv[2]=t0.z;xv[3]=t0.w;xv[4]=t1.x;xv[5]=t1.y;xv[6]=t1.z;xv[7]=t1.w; }
  unpack8(*(const uint4*)(sr + idx), s8);
  #pragma unroll
  for (int j = 0; j < 8; j++) o[j] = xv[j] + s8[j] * (a[j] + b[j]);
  if (fl) {
    float* q = (float*)out + idx;
    *(float4*)q = make_float4(o[0], o[1], o[2], o[3]);
    *(float4*)(q + 4) = make_float4(o[4], o[5], o[6], o[7]);
  } else {
    *(uint4*)((uint16_t*)out + idx) = pack8(o);
  }
}

// ---------------- WKV5 chunked ----------------
__global__ __launch_bounds__(256) void wkv_p_kernel(
    const uint16_t* __restrict__ kq, const uint16_t* __restrict__ vq,
    const void* __restrict__ wq, float* __restrict__ P,
    const int* __restrict__ dflag)
{
  int fl = *dflag;
  int blk = blockIdx.x;
  int c = blk & 15, h = (blk >> 4) & 31, b = blk >> 9;
  __shared__ __align__(16) float Kt[64][64];
  __shared__ __align__(16) uint16_t Vb[64][64];
  __shared__ __align__(16) float e_s[64];
  int tid = threadIdx.x;
  if (tid < 64) e_s[tid] = fminf(__expf(load1f(wq, h * 64 + tid, fl)), 100.f);
  __syncthreads();
  int rr = tid >> 3, cs = (tid & 7) * 8;
  #pragma unroll
  for (int p = 0; p < 2; p++) {
    int s = p * 32 + rr;
    size_t gbase = ((size_t)(b * TT + c * 64 + s)) * CC + h * 64 + cs;
    float k8[8];
    unpack8(*(const uint4*)(kq + gbase), k8);
    float sp = (float)(s + 1) * LOG2E;
    #pragma unroll
    for (int j = 0; j < 8; j++) Kt[s][cs + j] = k8[j] * exp2f(fminf(sp * e_s[cs + j], 80.f));
    *(uint4*)&Vb[s][cs] = *(const uint4*)(vq + gbase);
  }
  __syncthreads();
  int tx = tid & 15, ty = tid >> 4;
  int i0 = ty * 4, j0 = tx * 4;
  float acc[4][4] = {};
  for (int s = 0; s < 64; s++) {
    float4 a = *(const float4*)&Kt[s][i0];
    ushort4 vv = *(const ushort4*)&Vb[s][j0];
    float b0 = bf2f(vv.x), b1 = bf2f(vv.y), b2 = bf2f(vv.z), b3 = bf2f(vv.w);
    float am[4] = { a.x, a.y, a.z, a.w };
    #pragma unroll
    for (int m = 0; m < 4; m++) {
      acc[m][0] += am[m] * b0; acc[m][1] += am[m] * b1;
      acc[m][2] += am[m] * b2; acc[m][3] += am[m] * b3;
    }
  }
  float* Pb = P + (size_t)blk * 4096;
  #pragma unroll
  for (int m = 0; m < 4; m++) {
    float dl = exp2f(-64.0f * LOG2E * e_s[i0 + m]);
    float4 o = { acc[m][0] * dl, acc[m][1] * dl, acc[m][2] * dl, acc[m][3] * dl };
    *(float4*)&Pb[(i0 + m) * 64 + j0] = o;
  }
}

__global__ __launch_bounds__(256) void wkv_s_kernel(const float* __restrict__ P,
    const void* __restrict__ wq, float* __restrict__ S,
    const int* __restrict__ dflag)
{
  int fl = *dflag;
  int bh = blockIdx.x;
  int h = bh & 31;
  int tid = threadIdx.x;
  int i = tid >> 2, q = tid & 3;
  float e = fminf(__expf(load1f(wq, h * 64 + i, fl)), 100.f);
  float dl = exp2f(-64.0f * LOG2E * e);
  float4 s0 = {0,0,0,0}, s1 = {0,0,0,0}, s2 = {0,0,0,0}, s3 = {0,0,0,0};
  for (int c = 0; c < 16; c++) {
    size_t base = ((size_t)bh * 16 + c) * 4096 + (size_t)i * 64 + q * 16;
    *(float4*)&S[base + 0]  = s0;
    *(float4*)&S[base + 4]  = s1;
    *(float4*)&S[base + 8]  = s2;
    *(float4*)&S[base + 12] = s3;
    float4 p0 = *(const float4*)&P[base + 0];
    float4 p1 = *(const float4*)&P[base + 4];
    float4 p2 = *(const float4*)&P[base + 8];
    float4 p3 = *(const float4*)&P[base + 12];
    s0 = make_float4(dl * s0.x + p0.x, dl * s0.y + p0.y, dl * s0.z + p0.z, dl * s0.w + p0.w);
    s1 = make_float4(dl * s1.x + p1.x, dl * s1.y + p1.y, dl * s1.z + p1.z, dl * s1.w + p1.w);
    s2 = make_float4(dl * s2.x + p2.x, dl * s2.y + p2.y, dl * s2.z + p2.z, dl * s2.w + p2.w);
    s3 = make_float4(dl * s3.x + p3.x, dl * s3.y + p3.y, dl * s3.z + p3.z, dl * s3.w + p3.w);
  }
}

__global__ __launch_bounds__(256, 2) void wkv_y_kernel(
    const uint16_t* __restrict__ rq, const uint16_t* __restrict__ kq,
    const uint16_t* __restrict__ vq, const void* __restrict__ wq,
    const void* __restrict__ uq, const float* __restrict__ S,
    float* __restrict__ att, const int* __restrict__ dflag)
{
  int fl = *dflag;
  int blk = blockIdx.x;
  int c = blk & 15, h = (blk >> 4) & 31, b = blk >> 9;
  __shared__ __align__(16) float Rt[64][64];
  __shared__ __align__(16) float Kt[64][64];
  __shared__ __align__(16) uint16_t Vb[64][64];
  __shared__ __align__(16) float Ss[64][64];
  __shared__ __align__(16) float e_s[64];
  __shared__ __align__(16) float ud_s[64];
  int tid = threadIdx.x;
  if (tid < 64) {
    float e = fminf(__expf(load1f(wq, h * 64 + tid, fl)), 100.f);
    e_s[tid] = e;
    ud_s[tid] = load1f(uq, h * 64 + tid, fl) * __expf(-e);
  }
  __syncthreads();
  int rr = tid >> 3, cs = (tid & 7) * 8;
  #pragma unroll
  for (int p = 0; p < 2; p++) {
    int s = p * 32 + rr;
    size_t gbase = ((size_t)(b * TT + c * 64 + s)) * CC + h * 64 + cs;
    float r8[8], k8[8];
    unpack8(*(const uint4*)(rq + gbase), r8);
    unpack8(*(const uint4*)(kq + gbase), k8);
    float tneg = -(float)s * LOG2E;
    float spos = (float)(s + 1) * LOG2E;
    #pragma unroll
    for (int j = 0; j < 8; j++) {
      float e = e_s[cs + j];
      Rt[s][cs + j] = r8[j] * exp2f(tneg * e);
      Kt[s][cs + j] = k8[j] * exp2f(fminf(spos * e, 80.f));
    }
    *(uint4*)&Vb[s][cs] = *(const uint4*)(vq + gbase);
  }
  {
    int r2 = tid >> 2, q = tid & 3;
    const float* Sbp = S + (size_t)blk * 4096 + (size_t)r2 * 64 + q * 16;
    *(float4*)&Ss[r2][q * 16 + 0]  = *(const float4*)&Sbp[0];
    *(float4*)&Ss[r2][q * 16 + 4]  = *(const float4*)&Sbp[4];
    *(float4*)&Ss[r2][q * 16 + 8]  = *(const float4*)&Sbp[8];
    *(float4*)&Ss[r2][q * 16 + 12] = *(const float4*)&Sbp[12];
  }
  __syncthreads();
  int tx = tid & 15, ty = tid >> 4;
  int t0 = ty * 4, s0 = tx * 4;
  float acc[4][4] = {};
  for (int iq = 0; iq < 16; iq++) {
    int i = iq * 4;
    float4 ra[4], kb[4];
    #pragma unroll
    for (int m = 0; m < 4; m++) ra[m] = *(const float4*)&Rt[t0 + m][i];
    #pragma unroll
    for (int n = 0; n < 4; n++) kb[n] = *(const float4*)&Kt[s0 + n][i];
    #pragma unroll
    for (int m = 0; m < 4; m++)
      #pragma unroll
      for (int n = 0; n < 4; n++)
        acc[m][n] += ra[m].x * kb[n].x + ra[m].y * kb[n].y + ra[m].z * kb[n].z + ra[m].w * kb[n].w;
  }
  float dg = 0.f;
  if (tid < 64) {
    for (int iq = 0; iq < 16; iq++) {
      int i = iq * 4;
      float4 a = *(const float4*)&Rt[tid][i];
      float4 kk = *(const float4*)&Kt[tid][i];
      float4 u4 = *(const float4*)&ud_s[i];
      dg += a.x * kk.x * u4.x + a.y * kk.y * u4.y + a.z * kk.z * u4.z + a.w * kk.w * u4.w;
    }
  }
  __syncthreads();
  #pragma unroll
  for (int m = 0; m < 4; m++)
    #pragma unroll
    for (int n = 0; n < 4; n++) {
      int t = t0 + m, s = s0 + n;
      Kt[t][s] = (s < t) ? acc[m][n] : 0.0f;
    }
  __syncthreads();
  if (tid < 64) Kt[tid][tid] = dg;
  __syncthreads();
  int j0 = tx * 4;
  float y[4][4] = {};
  for (int sq = 0; sq < 16; sq++) {
    int s = sq * 4;
    float4 a4[4];
    #pragma unroll
    for (int m = 0; m < 4; m++) a4[m] = *(const float4*)&Kt[t0 + m][s];
    float vb[4][4];
    #pragma unroll
    for (int qq = 0; qq < 4; qq++) {
      ushort4 vv = *(const ushort4*)&Vb[s + qq][j0];
      vb[qq][0] = bf2f(vv.x); vb[qq][1] = bf2f(vv.y); vb[qq][2] = bf2f(vv.z); vb[qq][3] = bf2f(vv.w);
    }
    #pragma unroll
    for (int m = 0; m < 4; m++)
      #pragma unroll
      for (int n = 0; n < 4; n++)
        y[m][n] += a4[m].x * vb[0][n] + a4[m].y * vb[1][n] + a4[m].z * vb[2][n] + a4[m].w * vb[3][n];
  }
  for (int iq = 0; iq < 16; iq++) {
    int i = iq * 4;
    float4 r4[4], s4[4];
    #pragma unroll
    for (int m = 0; m < 4; m++) r4[m] = *(const float4*)&Rt[t0 + m][i];
    #pragma unroll
    for (int qq = 0; qq < 4; qq++) s4[qq] = *(const float4*)&Ss[i + qq][j0];
    #pragma unroll
    for (int m = 0; m < 4; m++)
      #pragma unroll
      for (int n = 0; n < 4; n++)
        y[m][n] += r4[m].x * s4[0][n] + r4[m].y * s4[1][n] + r4[m].z * s4[2][n] + r4[m].w * s4[3][n];
  }
  #pragma unroll
  for (int m = 0; m < 4; m++) {
    size_t ob = ((size_t)(b * TT + c * 64 + t0 + m)) * CC + h * 64 + j0;
    *(float4*)&att[ob] = make_float4(y[m][0], y[m][1], y[m][2], y[m][3]);
  }
}

// ---------------- GroupNorm(att/8) * g ----------------
__global__ __launch_bounds__(256) void gn_mul_kernel(const float* __restrict__ att,
    const void* __restrict__ gg, const void* __restrict__ bb,
    const uint16_t* __restrict__ gate, uint16_t* __restrict__ out,
    const int* __restrict__ dflag)
{
  int fl = *dflag;
  int row = blockIdx.x;
  int tid = threadIdx.x;
  size_t base = (size_t)row * CC + (size_t)tid * 8;
  float4 a0 = *(const float4*)(att + base);
  float4 a1 = *(const float4*)(att + base + 4);
  float v[8] = { a0.x, a0.y, a0.z, a0.w, a1.x, a1.y, a1.z, a1.w };
  #pragma unroll
  for (int j = 0; j < 8; j++) v[j] *= 0.125f;
  float s = 0.f, s2 = 0.f;
  #pragma unroll
  for (int j = 0; j < 8; j++) { s += v[j]; s2 += v[j] * v[j]; }
  s += __shfl_xor(s, 1); s += __shfl_xor(s, 2); s += __shfl_xor(s, 4);
  s2 += __shfl_xor(s2, 1); s2 += __shfl_xor(s2, 2); s2 += __shfl_xor(s2, 4);
  float m = s * (1.f / 64.f);
  float var = s2 * (1.f / 64.f) - m * m;
  float rstd = rsqrtf(fmaxf(var, 0.f) + LNEPS);
  int c = tid * 8;
  float g8[8], b8[8], gt8[8], o[8];
  load8f(gg, c, fl, g8);
  load8f(bb, c, fl, b8);
  unpack8(*(const uint4*)(gate + base), gt8);
  #pragma unroll
  for (int j = 0; j < 8; j++) o[j] = ((v[j] - m) * rstd * g8[j] + b8[j]) * gt8[j];
  *(uint4*)(out + base) = pack8(o);
}

// ---------------- launch ----------------
extern "C" void kernel_launch(void* const* d_in, const int* in_sizes, int n_in,
                              void* d_out, int out_size, void* d_ws, size_t ws_size,
                              hipStream_t stream)
{
  const void* x    = d_in[0];
  const void* ln1g = d_in[1];
  const void* ln1b = d_in[2];
  const void* ln2g = d_in[3];
  const void* ln2b = d_in[4];
  const void* tmk  = d_in[5];
  const void* tmv  = d_in[6];
  const void* tmr  = d_in[7];
  const void* tmg  = d_in[8];
  const void* tdec = d_in[9];
  const void* tfaa = d_in[10];
  const void* Wr   = d_in[11];
  const void* Wk   = d_in[12];
  const void* Wv   = d_in[13];
  const void* Wg   = d_in[14];
  const void* Wo   = d_in[15];
  const void* lnxg = d_in[16];
  const void* lnxb = d_in[17];
  const void* fmk  = d_in[18];
  const void* fmr  = d_in[19];
  const void* Wkey = d_in[20];
  const void* Wrec = d_in[21];
  const void* Wval = d_in[22];

  char* ws = (char*)d_ws;
  const size_t SL  = (size_t)MTOT * CC;
  const size_t SLW = (size_t)CC * CC;
  uint16_t* XL    = (uint16_t*)(ws + 0);            // 8 MiB: xl / xl2 / WrecT
  uint16_t* WRECT = XL;                             // alias (xl2 dead after mix2)
  uint16_t* MIX4  = (uint16_t*)(ws + 8388608);      // 32 MiB: mixes / PART
  float*    PART  = (float*)   (ws + 8388608);      // alias (ck dead after FF2)
  uint16_t* RKVG  = (uint16_t*)(ws + 41943040);     // 32 MiB
  float*    ATT   = (float*)   (ws + 75497472);     // 16 MiB (aliased as X1)
  float*    X1    = ATT;
  float*    Pb    = (float*)   (ws + 92274688);     // 16 MiB
  float*    Sb    = (float*)   (ws + 109051904);    // 16 MiB
  uint16_t* KK    = (uint16_t*)(ws + 92274688);     // 32 MiB, alias P+S (dead)
  uint16_t* WT    = (uint16_t*)(ws + 125829120);    // 32 MiB
  int*      FLAG  = (int*)     (ws + 159383552);
  (void)in_sizes; (void)n_in; (void)out_size; (void)ws_size;

  // 0. dtype probe
  probe_kernel<<<dim3(1), 64, 0, stream>>>((const uint16_t*)x, FLAG);
  // 1. LN1
  ln_kernel<0><<<dim3(MTOT), 256, 0, stream>>>(x, ln1g, ln1b, XL, FLAG);
  // 2. transposes Wr,Wk,Wv,Wg -> WT slots 0..3 (one launch)
  transpose4_kernel<<<dim3(32, 32, 4), 256, 0, stream>>>(Wr, Wk, Wv, Wg, WT, FLAG);
  // 3. mixes (slices r,k,v,g)
  mix4_kernel<<<dim3(2048), 256, 0, stream>>>(XL, tmr, tmk, tmv, tmg, MIX4, FLAG);
  // 4. batched GEMM: r,k,v,g (silu on g)
  gemm_kernel<EPI_RKVG><<<dim3(16, 16, 4), 256, 0, stream>>>(MIX4, WT, (void*)RKVG, CC, CC, CC,
      nullptr, nullptr, nullptr, nullptr, nullptr, FLAG);
  // 5. WKV5 chunked
  wkv_p_kernel<<<dim3(1024), 256, 0, stream>>>(RKVG + 1 * SL, RKVG + 2 * SL, tdec, Pb, FLAG);
  wkv_s_kernel<<<dim3(64), 256, 0, stream>>>(Pb, tdec, Sb, FLAG);
  wkv_y_kernel<<<dim3(1024), 256, 0, stream>>>(RKVG + 0 * SL, RKVG + 1 * SL, RKVG + 2 * SL, tdec, tfaa, Sb, ATT, FLAG);
  // 6. GroupNorm(att/8)*g -> MIX4 slot0
  gn_mul_kernel<<<dim3(MTOT), 256, 0, stream>>>(ATT, lnxg, lnxb, RKVG + 3 * SL, MIX4, FLAG);
  // 7. Wo GEMM + residual -> X1 (f32)
  transpose_kernel<<<dim3(32, 32), 256, 0, stream>>>(Wo, WT, CC, CC, FLAG);
  gemm_kernel<EPI_RESID><<<dim3(16, 16), 256, 0, stream>>>(MIX4, WT, (void*)X1, CC, CC, CC,
      x, nullptr, nullptr, nullptr, nullptr, FLAG);
  // 8. LN2 -> XL (reuse)
  ln_kernel<1><<<dim3(MTOT), 256, 0, stream>>>(X1, ln2g, ln2b, XL, FLAG);
  // 9. mixes ck (MIX4 slot0), cr (RKVG slot0)
  mix2_kernel<<<dim3(2048), 256, 0, stream>>>(XL, fmk, fmr, MIX4, RKVG, FLAG);
  // 10. transposes for FF: Wkey -> WT, Wrec -> WRECT (XL region, xl2 dead)
  transpose_kernel<<<dim3(FFD / 64, CC / 64), 256, 0, stream>>>(Wkey, WT, CC, FFD, FLAG);
  transpose_kernel<<<dim3(32, 32), 256, 0, stream>>>(Wrec, WRECT, CC, CC, FLAG);
  // 11. fused FF GEMMs: kk = relu(ck@Wkey)^2 AND sr = sigmoid(cr@Wrec)
  gemm_kernel<EPI_FF2><<<dim3(80, 16), 256, 0, stream>>>(MIX4, WT, (void*)KK, FFD, CC, CC,
      nullptr, nullptr, RKVG, WRECT, (void*)(RKVG + 2 * SL), FLAG);
  // 12. Wval GEMM split-K=2 -> PART (f32, 2 x 16 MiB in dead MIX4 region)
  transpose_kernel<<<dim3(CC / 64, FFD / 64), 256, 0, stream>>>(Wval, WT, FFD, CC, FLAG);
  gemm_kernel<EPI_PART><<<dim3(16, 16, 2), 256, 0, stream>>>(KK, WT, (void*)PART, CC, FFD, FFD / 2,
      nullptr, nullptr, nullptr, nullptr, nullptr, FLAG);
  // 13. reduce: out = X1 + sr * (P0 + P1)
  final_reduce_kernel<<<dim3(2048), 256, 0, stream>>>(PART, X1, RKVG + 2 * SL, d_out, FLAG);
}